// Round 1
// baseline (215.628 us; speedup 1.0000x reference)
//
#include <hip/hip_runtime.h>
#include <math.h>

#define NQ 6
#define NL 3
#define DIM 64

__global__ __launch_bounds__(256)
void qsim_kernel(const float* __restrict__ x, const float* __restrict__ w,
                 float* __restrict__ out, int B) {
    int b = blockIdx.x * blockDim.x + threadIdx.x;
    if (b >= B) return;

    // ---- load x[b][0..5] via 3x float2 (24B row, 8B aligned) ----
    const float2* x2 = (const float2*)x;
    float2 v0 = x2[b * 3 + 0];
    float2 v1 = x2[b * 3 + 1];
    float2 v2 = x2[b * 3 + 2];
    float xi[NQ] = {v0.x, v0.y, v1.x, v1.y, v2.x, v2.y};

    // ---- per-sample RY angles: phi_i = 0.5*pi*tanh(x_i); c=cos(phi), s=sin(phi) ----
    float C[NQ], S[NQ];
#pragma unroll
    for (int i = 0; i < NQ; i++) {
        float ph = 0.5f * 3.14159265358979f * tanhf(xi[i]);
        __sincosf(ph, &S[i], &C[i]);
    }

    // ---- state in registers: |0...0> ----
    float sr[DIM], si[DIM];
#pragma unroll
    for (int k = 0; k < DIM; k++) { sr[k] = 0.0f; si[k] = 0.0f; }
    sr[0] = 1.0f;

#pragma unroll
    for (int layer = 0; layer < NL; layer++) {
#pragma unroll
        for (int q = 0; q < NQ; q++) {
            // M = RZ(a2) @ RY(a1) @ RZ(a0)  (uniform across threads; w is tiny)
            float a0 = w[(layer * NQ + q) * 3 + 0];
            float a1 = w[(layer * NQ + q) * 3 + 1];
            float a2 = w[(layer * NQ + q) * 3 + 2];
            float ch, sh, cp, sp, cm, sm;
            __sincosf(0.5f * a1, &sh, &ch);
            __sincosf(0.5f * (a0 + a2), &sp, &cp);
            __sincosf(0.5f * (a0 - a2), &sm, &cm);
            // m00 = ch*e^{-ip}, m01 = -sh*e^{+im}, m10 = sh*e^{-im}, m11 = ch*e^{+ip}
            float m00r =  ch * cp, m00i = -ch * sp;
            float m01r = -sh * cm, m01i = -sh * sm;
            float m10r =  sh * cm, m10i = -sh * sm;
            float m11r =  ch * cp, m11i =  ch * sp;
            // G = M @ RY(phi_q): per-thread fused gate
            float c = C[q], s = S[q];
            float g00r =  m00r * c + m01r * s, g00i =  m00i * c + m01i * s;
            float g01r = -m00r * s + m01r * c, g01i = -m00i * s + m01i * c;
            float g10r =  m10r * c + m11r * s, g10i =  m10i * c + m11i * s;
            float g11r = -m10r * s + m11r * c, g11i = -m10i * s + m11i * c;

            // apply on wire q: bit position (5-q); stride = right
            const int right = 1 << (5 - q);
            const int left  = 1 << q;
#pragma unroll
            for (int l = 0; l < left; l++) {
#pragma unroll
                for (int r = 0; r < right; r++) {
                    const int i0 = (l * 2) * right + r;
                    const int i1 = i0 + right;
                    float ar = sr[i0], ai = si[i0];
                    float br = sr[i1], bi = si[i1];
                    sr[i0] = g00r * ar - g00i * ai + g01r * br - g01i * bi;
                    si[i0] = g00r * ai + g00i * ar + g01r * bi + g01i * br;
                    sr[i1] = g10r * ar - g10i * ai + g11r * br - g11i * bi;
                    si[i1] = g10r * ai + g10i * ar + g11r * bi + g11i * br;
                }
            }
        }
        // ---- CNOT ring: (0,1),(1,2),(2,3),(3,4),(4,5),(5,0) ----
        // new[k] = old[k ^ tb] when control bit set => swap within control=1 slab.
        // Pure register permutation (compile-time indices).
#pragma unroll
        for (int e = 0; e < NQ; e++) {
            const int ctrl = e;
            const int tgt  = (e + 1) % NQ;
            const int cb = 1 << (5 - ctrl);
            const int tb = 1 << (5 - tgt);
#pragma unroll
            for (int k = 0; k < DIM; k++) {
                if ((k & cb) && !(k & tb)) {
                    const int k2 = k | tb;
                    float tr = sr[k]; sr[k] = sr[k2]; sr[k2] = tr;
                    float ti = si[k]; si[k] = si[k2]; si[k2] = ti;
                }
            }
        }
    }

    // ---- expvals: out[q] = sum_k (1 - 2*bit_q(k)) * |amp_k|^2 ----
    float acc[NQ] = {0.f, 0.f, 0.f, 0.f, 0.f, 0.f};
#pragma unroll
    for (int k = 0; k < DIM; k++) {
        float p = sr[k] * sr[k] + si[k] * si[k];
#pragma unroll
        for (int q = 0; q < NQ; q++) {
            if (k & (1 << (5 - q))) acc[q] -= p; else acc[q] += p;
        }
    }
    float2* o2 = (float2*)out;
    o2[b * 3 + 0] = make_float2(acc[0], acc[1]);
    o2[b * 3 + 1] = make_float2(acc[2], acc[3]);
    o2[b * 3 + 2] = make_float2(acc[4], acc[5]);
}

extern "C" void kernel_launch(void* const* d_in, const int* in_sizes, int n_in,
                              void* d_out, int out_size, void* d_ws, size_t ws_size,
                              hipStream_t stream) {
    const float* x = (const float*)d_in[0];
    const float* w = (const float*)d_in[1];
    float* out = (float*)d_out;
    int B = in_sizes[0] / NQ;
    int block = 256;
    int grid = (B + block - 1) / block;
    qsim_kernel<<<grid, block, 0, stream>>>(x, w, out, B);
}